// Round 1
// baseline (3392.125 us; speedup 1.0000x reference)
//
#include <hip/hip_runtime.h>
#include <stdint.h>

#define TN_D 1024
#define TN_F 1024
#define SENT32 0xAAAAAAAAu
#define NBLK 64
#define CPB 16            // intermediate elements owned per block (1 per wave)
#define NR (TN_F / 2)     // fused rounds: each round advances the chain 2 steps
#define CNT_STRIDE 16     // dwords per round-counter (64B padding, own line)

typedef _Float16 half8_t __attribute__((ext_vector_type(8)));
typedef _Float16 half4_t __attribute__((ext_vector_type(4)));

// ---------------------------------------------------------------------------
// Transpose + convert: core[s][i][j] f32 -> coreT[s][j][i] f16.
// ---------------------------------------------------------------------------
__global__ __launch_bounds__(256) void tn_transpose(const float* __restrict__ core,
                                                    _Float16* __restrict__ coreT) {
    __shared__ float tile[64][65];
    const int s = blockIdx.z;
    const size_t base = (size_t)s * TN_D * TN_D;
    const int j0 = blockIdx.x * 64;
    const int i0 = blockIdx.y * 64;
    const int tx = threadIdx.x;
    const int ty = threadIdx.y;
#pragma unroll
    for (int r = 0; r < 4; ++r) {
        const int ii = ty + 16 * r;
        const float4 v = *(const float4*)&core[base + (size_t)(i0 + ii) * TN_D + j0 + 4 * tx];
        tile[ii][4 * tx + 0] = v.x; tile[ii][4 * tx + 1] = v.y;
        tile[ii][4 * tx + 2] = v.z; tile[ii][4 * tx + 3] = v.w;
    }
    __syncthreads();
#pragma unroll
    for (int r = 0; r < 4; ++r) {
        const int jj = ty + 16 * r;
        _Float16 h4[4];
        h4[0] = (_Float16)tile[4 * tx + 0][jj];
        h4[1] = (_Float16)tile[4 * tx + 1][jj];
        h4[2] = (_Float16)tile[4 * tx + 2][jj];
        h4[3] = (_Float16)tile[4 * tx + 3][jj];
        *(uint64_t*)&coreT[base + (size_t)(j0 + jj) * TN_D + i0 + 4 * tx] = *(uint64_t*)h4;
    }
}

__device__ __forceinline__ float dot4h(float4 a, half4_t h) {
    return a.x * (float)h[0] + a.y * (float)h[1] + a.z * (float)h[2] + a.w * (float)h[3];
}

// Depth-2 pipelined poll until counter reaches NBLK (values only grow to NBLK).
__device__ __forceinline__ void poll_cnt(const uint32_t* cp) {
    uint32_t a = __hip_atomic_load(cp, __ATOMIC_RELAXED, __HIP_MEMORY_SCOPE_AGENT);
    uint32_t b = __hip_atomic_load(cp, __ATOMIC_RELAXED, __HIP_MEMORY_SCOPE_AGENT);
    while (a < NBLK) {
        a = b;
        b = __hip_atomic_load(cp, __ATOMIC_RELAXED, __HIP_MEMORY_SCOPE_AGENT);
    }
}

// ---------------------------------------------------------------------------
// Fused 2-step chain. Per round r (steps 2r, 2r+1):
//   gather:  wave w computes w_b[w] = v . coreT[s0][16b+w][:]   (conflict-free
//            b128 LDS reads: lane l handles elements {4l,256+4l,512+4l,768+4l})
//   scatter: thread j adds  sum_m w_b[m]*coreT[s1][j][16b+m]  into acc[r][j]
//            via device-scope f32 atomicAdd (performed at the coherence point)
//   signal:  per-wave vmcnt(0) drain -> barrier -> one RELEASE increment of
//            cnt[r]; consumers poll cnt (wave0 only, 1 txn/iter) then read acc
//            with relaxed agent atomic loads (issued strictly after the poll
//            observed 64, which producers ordered after their drained adds).
// Max inter-block skew is 1 round (round r+1 gates on cnt[r]), so lv/wl reuse
// across rounds is safe under the per-round barriers.
// ---------------------------------------------------------------------------
__global__ __launch_bounds__(1024, 1) void tn_chain2(const int* __restrict__ x,
                                                     const _Float16* __restrict__ mat,
                                                     const float* __restrict__ left,
                                                     const float* __restrict__ right,
                                                     float* __restrict__ acc,
                                                     uint32_t* __restrict__ cnt,
                                                     float* __restrict__ out) {
    __shared__ __align__(16) float lv[TN_D];  // broadcast v_t
    __shared__ __align__(16) float wl[CPB];   // this block's slice of v_{t+1}
    __shared__ int xs[TN_F];

    const int tid = threadIdx.x;
    const int w = tid >> 6;
    const int l = tid & 63;
    const int b = blockIdx.x;

    xs[tid] = x[tid];
    __syncthreads();

    // round-0 fragments
    half4_t A0, A1, A2, A3;
    half8_t B0, B1;
    {
        const half4_t* cA = (const half4_t*)(mat + ((size_t)xs[0] * TN_D + (CPB * b + w)) * TN_D);
        A0 = cA[l]; A1 = cA[64 + l]; A2 = cA[128 + l]; A3 = cA[192 + l];
        const half8_t* cB = (const half8_t*)(mat + ((size_t)xs[1] * TN_D + tid) * TN_D + CPB * b);
        B0 = cB[0]; B1 = cB[1];
    }

#pragma unroll 1
    for (int r = 0; r < NR; ++r) {
        // prefetch next round's fragments (off critical path; drained by the
        // first value-use after the poll, long before the vmcnt(0) below)
        half4_t nA0, nA1, nA2, nA3;
        half8_t nB0, nB1;
        {
            const int i2 = 2 * r + 2;
            const int sA = xs[(i2 < TN_F) ? i2 : 0];
            const int sB = xs[(i2 + 1 < TN_F) ? i2 + 1 : 0];
            const half4_t* cA = (const half4_t*)(mat + ((size_t)sA * TN_D + (CPB * b + w)) * TN_D);
            nA0 = cA[l]; nA1 = cA[64 + l]; nA2 = cA[128 + l]; nA3 = cA[192 + l];
            const half8_t* cB = (const half8_t*)(mat + ((size_t)sB * TN_D + tid) * TN_D + CPB * b);
            nB0 = cB[0]; nB1 = cB[1];
        }

        // ---- acquire v_{2r} ----
        if (r == 0) {
            lv[tid] = left[tid];
        } else {
            if (w == 0) poll_cnt(cnt + (size_t)(r - 1) * CNT_STRIDE);
            __syncthreads();  // nobody reads acc before the count is confirmed
            lv[tid] = __hip_atomic_load(acc + (size_t)(r - 1) * TN_D + tid,
                                        __ATOMIC_RELAXED, __HIP_MEMORY_SCOPE_AGENT);
        }
        __syncthreads();

        // ---- phase A: gather (conflict-free b128 pattern) ----
        const float4* vv = (const float4*)lv;
        const float4 v0 = vv[l], v1 = vv[64 + l], v2 = vv[128 + l], v3 = vv[192 + l];
        float s = dot4h(v0, A0) + dot4h(v1, A1) + dot4h(v2, A2) + dot4h(v3, A3);
#pragma unroll
        for (int off = 32; off; off >>= 1) s += __shfl_down(s, off, 64);
        if (l == 0) wl[w] = s;
        __syncthreads();

        // ---- phase B: scatter partial of v_{2r+2} ----
        const float4* w4 = (const float4*)wl;  // broadcast reads, conflict-free
        const float4 W0 = w4[0], W1 = w4[1], W2 = w4[2], W3 = w4[3];
        float p = W0.x * (float)B0[0] + W0.y * (float)B0[1] + W0.z * (float)B0[2] + W0.w * (float)B0[3]
                + W1.x * (float)B0[4] + W1.y * (float)B0[5] + W1.z * (float)B0[6] + W1.w * (float)B0[7]
                + W2.x * (float)B1[0] + W2.y * (float)B1[1] + W2.z * (float)B1[2] + W2.w * (float)B1[3]
                + W3.x * (float)B1[4] + W3.y * (float)B1[5] + W3.z * (float)B1[6] + W3.w * (float)B1[7];
        atomicAdd(acc + (size_t)r * TN_D + tid, p);
        __asm__ volatile("s_waitcnt vmcnt(0)" ::: "memory");  // add performed at IC
        __syncthreads();                                      // all waves drained
        if (tid == 0)
            __hip_atomic_fetch_add(cnt + (size_t)r * CNT_STRIDE, 1u,
                                   __ATOMIC_RELEASE, __HIP_MEMORY_SCOPE_AGENT);

        A0 = nA0; A1 = nA1; A2 = nA2; A3 = nA3; B0 = nB0; B1 = nB1;
    }

    // ---- final dot with right boundary: block 0 ----
    if (b == 0) {
        if (w == 0) poll_cnt(cnt + (size_t)(NR - 1) * CNT_STRIDE);
        __syncthreads();
        const float v = __hip_atomic_load(acc + (size_t)(NR - 1) * TN_D + tid,
                                          __ATOMIC_RELAXED, __HIP_MEMORY_SCOPE_AGENT);
        float p = v * right[tid];
#pragma unroll
        for (int off = 32; off; off >>= 1) p += __shfl_down(p, off, 64);
        if (l == 0) wl[w] = p;
        __syncthreads();
        if (tid == 0) {
            float t = 0.f;
#pragma unroll
            for (int k = 0; k < CPB; ++k) t += wl[k];
            out[0] = t;
        }
    }
}

// ---------------------------------------------------------------------------
// Fallback (tiny workspace): R2-structure fp32, no transpose.
// ---------------------------------------------------------------------------
__device__ __forceinline__ float4 poll4(const uint32_t* vp) {
    const unsigned long long* p = (const unsigned long long*)vp;
    unsigned long long a = __hip_atomic_load(p, __ATOMIC_RELAXED, __HIP_MEMORY_SCOPE_AGENT);
    unsigned long long b = __hip_atomic_load(p + 1, __ATOMIC_RELAXED, __HIP_MEMORY_SCOPE_AGENT);
    while ((uint32_t)a == SENT32 || (uint32_t)(a >> 32) == SENT32)
        a = __hip_atomic_load(p, __ATOMIC_RELAXED, __HIP_MEMORY_SCOPE_AGENT);
    while ((uint32_t)b == SENT32 || (uint32_t)(b >> 32) == SENT32)
        b = __hip_atomic_load(p + 1, __ATOMIC_RELAXED, __HIP_MEMORY_SCOPE_AGENT);
    return make_float4(__uint_as_float((uint32_t)a), __uint_as_float((uint32_t)(a >> 32)),
                       __uint_as_float((uint32_t)b), __uint_as_float((uint32_t)(b >> 32)));
}

__global__ __launch_bounds__(256, 1) void tn_chain_f32(const int* __restrict__ x,
                                                       const float* __restrict__ mat,
                                                       const float* __restrict__ left,
                                                       const float* __restrict__ right,
                                                       float* __restrict__ vg,
                                                       float* __restrict__ out) {
    __shared__ float4 lv[2][TN_D / 4];
    __shared__ float red[4];
    const int tid = threadIdx.x;
    const int w = tid >> 6;
    const int l = tid & 63;
    const int j = blockIdx.x * 4 + w;

    for (int t = 0; t < TN_F; ++t) {
        if (t == 0) lv[0][tid] = ((const float4*)left)[tid];
        else lv[t & 1][tid] = poll4((const uint32_t*)vg + (size_t)(t - 1) * TN_D + 4 * tid);
        __syncthreads();
        const float* mp = mat + (size_t)x[t] * TN_D * TN_D + j;
        const float4* vv = lv[t & 1];
        float acc = 0.f;
#pragma unroll
        for (int k = 0; k < 4; ++k) {
            const int i = 4 * l + 256 * k;
            const float4 v = vv[l + 64 * k];
            acc += v.x * mp[(size_t)i * TN_D] + v.y * mp[(size_t)(i + 1) * TN_D] +
                   v.z * mp[(size_t)(i + 2) * TN_D] + v.w * mp[(size_t)(i + 3) * TN_D];
        }
#pragma unroll
        for (int off = 32; off; off >>= 1) acc += __shfl_down(acc, off, 64);
        if (l == 0)
            __hip_atomic_store((uint32_t*)vg + (size_t)t * TN_D + j, __float_as_uint(acc),
                               __ATOMIC_RELAXED, __HIP_MEMORY_SCOPE_AGENT);
    }
    if (blockIdx.x == 0) {
        float4 v = poll4((const uint32_t*)vg + (size_t)(TN_F - 1) * TN_D + 4 * tid);
        const float4 r4 = ((const float4*)right)[tid];
        float p = v.x * r4.x + v.y * r4.y + v.z * r4.z + v.w * r4.w;
#pragma unroll
        for (int off = 32; off; off >>= 1) p += __shfl_down(p, off, 64);
        if (l == 0) red[w] = p;
        __syncthreads();
        if (tid == 0) out[0] = red[0] + red[1] + red[2] + red[3];
    }
}

extern "C" void kernel_launch(void* const* d_in, const int* in_sizes, int n_in,
                              void* d_out, int out_size, void* d_ws, size_t ws_size,
                              hipStream_t stream) {
    const int* x = (const int*)d_in[0];
    const float* core = (const float*)d_in[1];
    const float* left = (const float*)d_in[2];
    const float* right = (const float*)d_in[3];
    float* out = (float*)d_out;

    const int nsym = in_sizes[1] / (TN_D * TN_D);
    const size_t coreTBytes = (size_t)in_sizes[1] * sizeof(_Float16);            // 64 MB
    const size_t cntBytes = (size_t)NR * CNT_STRIDE * sizeof(uint32_t);          // 32 KB
    const size_t accBytes = (size_t)NR * TN_D * sizeof(float);                   // 2 MB

    if (ws_size >= coreTBytes + cntBytes + accBytes) {
        _Float16* coreT = (_Float16*)d_ws;
        uint32_t* cnt = (uint32_t*)((char*)d_ws + coreTBytes);
        float* acc = (float*)((char*)d_ws + coreTBytes + cntBytes);
        hipMemsetAsync(cnt, 0, cntBytes + accBytes, stream);
        tn_transpose<<<dim3(16, 16, nsym), dim3(16, 16), 0, stream>>>(core, coreT);
        tn_chain2<<<NBLK, 1024, 0, stream>>>(x, coreT, left, right, acc, cnt, out);
    } else {
        float* vg = (float*)d_ws;
        const size_t vbufBytes = (size_t)TN_F * TN_D * sizeof(float);
        hipMemsetAsync(vg, 0xAA, vbufBytes, stream);
        tn_chain_f32<<<256, 256, 0, stream>>>(x, core, left, right, vg, out);
    }
}